// Round 2
// baseline (445.098 us; speedup 1.0000x reference)
//
#include <hip/hip_runtime.h>
#include <cmath>

namespace {

constexpr int kDim = 5;
constexpr int kSave = 64;
constexpr int kTraj = 16;      // trajectories per block (= MFMA M)
constexpr int kThreads = 256;  // 4 waves; wave w owns neurons [16w, 16w+16)
constexpr int kMaxSteps = 64;
constexpr int LDD = 8;         // padded stride for dim-5 f32 rows
constexpr int HSTR = 72;       // f16 stride for 16x64 activation buffers (144B: 2-way banks, 16B aligned)
constexpr int ZSTR = 40;       // f16 stride for 16x32 zero-padded z buffer (80B)

typedef _Float16 half8 __attribute__((ext_vector_type(8)));
typedef float f32x4 __attribute__((ext_vector_type(4)));

__device__ __forceinline__ float softplusf(float x) {
  // jax.nn.softplus(x) = max(x,0) + log1p(exp(-|x|))
  return fmaxf(x, 0.0f) + log1pf(expf(-fabsf(x)));
}

__device__ __forceinline__ half8 h8zero() {
  half8 v;
  #pragma unroll
  for (int i = 0; i < 8; ++i) v[i] = (_Float16)0.0f;
  return v;
}

__global__ __launch_bounds__(kThreads)
void node_tsit5_kernel(const float* __restrict__ gy0,
                       const float* __restrict__ gte,
                       const float* __restrict__ gW1, const float* __restrict__ gb1,
                       const float* __restrict__ gW2, const float* __restrict__ gb2,
                       const float* __restrict__ gW3, const float* __restrict__ gb3,
                       const float* __restrict__ gW4, const float* __restrict__ gb4,
                       float* __restrict__ out) {
  const float A21 = 0.161f;
  const float A31 = -0.008480655492356989f, A32 = 0.335480655492357f;
  const float A41 = 2.8971530571054935f, A42 = -6.359448489975075f, A43 = 4.3622954328695815f;
  const float A51 = 5.325864828439257f, A52 = -11.748883564062828f, A53 = 7.4955393428898365f,
              A54 = -0.09249506636175525f;
  const float A61 = 5.86145544294642f, A62 = -12.92096931784711f, A63 = 8.159367898576159f,
              A64 = -0.071584973281401f, A65 = -0.028269050394068383f;
  const float B1 = 0.09646076681806523f, B2 = 0.01f, B3 = 0.4798896504144996f,
              B4 = 1.379008574103742f, B5 = -3.290069515436081f, B6 = 2.324710524099774f;
  const float E1 = -0.00178001105222577714f, E2 = -0.0008164344596567469f,
              E3 = 0.007880878010261995f, E4 = -0.1447110071732629f, E5 = 0.5823571654525552f,
              E6 = -0.45808210592918697f, E7 = 0.015151515151515152f;

  __shared__ __align__(16) _Float16 zb[kTraj * ZSTR];   // MLP input, A-layout, K padded to 32 w/ zeros
  __shared__ __align__(16) _Float16 hA[kTraj * HSTR];   // activations ping
  __shared__ __align__(16) _Float16 hB[kTraj * HSTR];   // activations pong
  __shared__ float sTe[kSave];
  __shared__ float sy[kTraj * LDD];
  __shared__ float syn[kTraj * LDD];
  __shared__ float sesq[kTraj * LDD];
  __shared__ float sk[7][kTraj * LDD];
  __shared__ float s_t[kTraj], s_h[kTraj], s_hc[kTraj], s_tn[kTraj], s_hn[kTraj];
  __shared__ int s_ok[kTraj], s_done[kTraj];
  __shared__ int s_alldone;

  const int tid = threadIdx.x;
  const int bid = blockIdx.x;
  const int w = tid >> 6;        // wave id (N-tile)
  const int ln = tid & 63;
  const int quad = ln >> 4;
  const int col = ln & 15;       // MFMA col: N-index within tile; also A-row m for frag loads
  const int nn = (w << 4) | col; // global neuron for this lane's B-frag / C-col
  const int tt = tid & 15;       // trajectory (interp phase)
  const int gg = tid >> 4;       // save-point group (interp phase)

  // ---- one-time: weight B-fragments into registers (f16), biases into VGPRs ----
  // B[k][n] = W[n][k]; lane holds k = kf*32 + quad*8 + j, n = nn.
  half8 bw1 = h8zero();
  if (quad == 0) {
    #pragma unroll
    for (int j = 0; j < kDim; ++j) bw1[j] = (_Float16)gW1[nn * kDim + j];
  }
  half8 bw2[2], bw3[2];
  #pragma unroll
  for (int kf = 0; kf < 2; ++kf) {
    const float* p2 = gW2 + nn * 64 + kf * 32 + quad * 8;
    const float* p3 = gW3 + nn * 64 + kf * 32 + quad * 8;
    #pragma unroll
    for (int j = 0; j < 8; ++j) { bw2[kf][j] = (_Float16)p2[j]; bw3[kf][j] = (_Float16)p3[j]; }
  }
  half8 bw4[2] = {h8zero(), h8zero()};
  float c4 = 0.0f;
  if (col < kDim) {
    c4 = gb4[col];
    #pragma unroll
    for (int kf = 0; kf < 2; ++kf) {
      const float* p4 = gW4 + col * 64 + kf * 32 + quad * 8;
      #pragma unroll
      for (int j = 0; j < 8; ++j) bw4[kf][j] = (_Float16)p4[j];
    }
  }
  const float c1 = gb1[nn], c2 = gb2[nn], c3 = gb3[nn];

  // ---- stage state into LDS ----
  if (tid < kSave) sTe[tid] = gte[tid];
  for (int i = tid; i < kTraj * ZSTR; i += kThreads) zb[i] = (_Float16)0.0f;
  if (tid < kTraj * kDim) {
    int t = tid & 15, d = tid >> 4;
    sy[t * LDD + d] = gy0[(bid * kTraj + t) * kDim + d];
  }
  if (tid < kTraj) { s_t[tid] = gte[0]; s_h[tid] = 0.1f; }
  {
    float* ob = out + (size_t)bid * kTraj * kSave * kDim;
    for (int idx = tid; idx < kTraj * kSave * kDim; idx += kThreads) ob[idx] = 0.0f;
  }
  __syncthreads();

  const float t0v = sTe[0];
  const float t1v = sTe[kSave - 1];

  // saves at/before t0 get y0; also seed zb with y0 for the first f-eval
  if (tid < kTraj * kDim) {
    int t = tid & 15, d = tid >> 4;
    float yv = sy[t * LDD + d];
    zb[t * ZSTR + d] = (_Float16)yv;
    for (int n = 0; n < kSave; ++n)
      if (sTe[n] <= t0v + 1e-6f)
        out[((size_t)(bid * kTraj + t) * kSave + n) * kDim + d] = yv;
  }
  __syncthreads();

  // dst = MLP(zb); uniformly executed; 4 internal barriers + trailing barrier
  auto evalF = [&](float* __restrict__ dstK) {
    // layer 1: 5 -> 64 (K padded to 32)
    half8 az = *(const half8*)(zb + col * ZSTR + quad * 8);
    f32x4 acc = {c1, c1, c1, c1};
    acc = __builtin_amdgcn_mfma_f32_16x16x32_f16(az, bw1, acc, 0, 0, 0);
    #pragma unroll
    for (int r = 0; r < 4; ++r)
      hA[(quad * 4 + r) * HSTR + nn] = (_Float16)softplusf(acc[r]);
    __syncthreads();
    // layer 2: 64 -> 64 (hA -> hB)
    {
      half8 a0 = *(const half8*)(hA + col * HSTR + quad * 8);
      half8 a1 = *(const half8*)(hA + col * HSTR + 32 + quad * 8);
      f32x4 a = {c2, c2, c2, c2};
      a = __builtin_amdgcn_mfma_f32_16x16x32_f16(a0, bw2[0], a, 0, 0, 0);
      a = __builtin_amdgcn_mfma_f32_16x16x32_f16(a1, bw2[1], a, 0, 0, 0);
      #pragma unroll
      for (int r = 0; r < 4; ++r)
        hB[(quad * 4 + r) * HSTR + nn] = (_Float16)softplusf(a[r]);
    }
    __syncthreads();
    // layer 3: 64 -> 64 (hB -> hA)
    {
      half8 a0 = *(const half8*)(hB + col * HSTR + quad * 8);
      half8 a1 = *(const half8*)(hB + col * HSTR + 32 + quad * 8);
      f32x4 a = {c3, c3, c3, c3};
      a = __builtin_amdgcn_mfma_f32_16x16x32_f16(a0, bw3[0], a, 0, 0, 0);
      a = __builtin_amdgcn_mfma_f32_16x16x32_f16(a1, bw3[1], a, 0, 0, 0);
      #pragma unroll
      for (int r = 0; r < 4; ++r)
        hA[(quad * 4 + r) * HSTR + nn] = (_Float16)softplusf(a[r]);
    }
    __syncthreads();
    // layer 4: 64 -> 5 (wave 0 only; cols >= 5 are garbage and never written)
    if (w == 0) {
      half8 a0 = *(const half8*)(hA + col * HSTR + quad * 8);
      half8 a1 = *(const half8*)(hA + col * HSTR + 32 + quad * 8);
      f32x4 a = {c4, c4, c4, c4};
      a = __builtin_amdgcn_mfma_f32_16x16x32_f16(a0, bw4[0], a, 0, 0, 0);
      a = __builtin_amdgcn_mfma_f32_16x16x32_f16(a1, bw4[1], a, 0, 0, 0);
      if (col < kDim) {
        #pragma unroll
        for (int r = 0; r < 4; ++r) dstK[(quad * 4 + r) * LDD + col] = a[r];
      }
    }
    __syncthreads();
  };

  // k1 = f(y0); thereafter FSAL: k1 <- (accepted ? k7 : k1) is bitwise identical
  evalF(sk[0]);

  for (int step = 0; step < kMaxSteps; ++step) {
    if (tid < kTraj) {
      float tc = s_t[tid];
      int dn = tc >= t1v - 1e-6f;
      s_done[tid] = dn;
      s_hc[tid] = dn ? 0.0f : fminf(s_h[tid], t1v - tc);
    }
    __syncthreads();
    if (tid == 0) {
      int ad = 1;
      for (int i = 0; i < kTraj; ++i) ad &= s_done[i];
      s_alldone = ad;
    }
    __syncthreads();
    if (s_alldone) break;   // uniform: all remaining iterations are no-ops

    const bool l80 = tid < kTraj * kDim;
    const int ut = tid & 15, ud = tid >> 4;
    const int uo = ut * LDD + ud;
    const int zo = ut * ZSTR + ud;
    float hcv = 0.f;
    if (l80) hcv = s_hc[ut];

    if (l80) zb[zo] = (_Float16)fmaf(hcv, A21 * sk[0][uo], sy[uo]);
    __syncthreads();
    evalF(sk[1]);

    if (l80) zb[zo] = (_Float16)fmaf(hcv, fmaf(A32, sk[1][uo], A31 * sk[0][uo]), sy[uo]);
    __syncthreads();
    evalF(sk[2]);

    if (l80) zb[zo] = (_Float16)fmaf(hcv,
                      fmaf(A43, sk[2][uo], fmaf(A42, sk[1][uo], A41 * sk[0][uo])), sy[uo]);
    __syncthreads();
    evalF(sk[3]);

    if (l80) zb[zo] = (_Float16)fmaf(hcv, fmaf(A54, sk[3][uo], fmaf(A53, sk[2][uo],
                      fmaf(A52, sk[1][uo], A51 * sk[0][uo]))), sy[uo]);
    __syncthreads();
    evalF(sk[4]);

    if (l80) zb[zo] = (_Float16)fmaf(hcv, fmaf(A65, sk[4][uo], fmaf(A64, sk[3][uo],
                      fmaf(A63, sk[2][uo], fmaf(A62, sk[1][uo], A61 * sk[0][uo])))), sy[uo]);
    __syncthreads();
    evalF(sk[5]);

    if (l80) {
      float v = fmaf(hcv, fmaf(B6, sk[5][uo], fmaf(B5, sk[4][uo], fmaf(B4, sk[3][uo],
                fmaf(B3, sk[2][uo], fmaf(B2, sk[1][uo], B1 * sk[0][uo]))))), sy[uo]);
      syn[uo] = v;
      zb[zo] = (_Float16)v;
    }
    __syncthreads();
    evalF(sk[6]);   // k7 (FSAL)

    if (l80) {
      float err = hcv * fmaf(E7, sk[6][uo], fmaf(E6, sk[5][uo], fmaf(E5, sk[4][uo],
                  fmaf(E4, sk[3][uo], fmaf(E3, sk[2][uo], fmaf(E2, sk[1][uo], E1 * sk[0][uo]))))));
      float sc = fmaf(1e-3f, fmaxf(fabsf(sy[uo]), fabsf(syn[uo])), 1e-6f);
      float r = err / sc;
      sesq[uo] = r * r;
    }
    __syncthreads();
    if (tid < kTraj) {
      float s = 0.f;
      #pragma unroll
      for (int d = 0; d < kDim; ++d) s += sesq[tid * LDD + d];
      float enorm = sqrtf(s / 5.0f);
      float enc = fmaxf(enorm, 1e-10f);
      int accept = enorm <= 1.0f;
      float factor = fminf(fmaxf(0.9f * powf(enc, -0.2f), 0.2f), 10.0f);
      int dn = s_done[tid];
      int ok = accept && !dn;
      float hcc = s_hc[tid];
      s_tn[tid] = ok ? s_t[tid] + hcc : s_t[tid];
      s_hn[tid] = dn ? s_h[tid] : hcc * factor;
      s_ok[tid] = ok;
    }
    __syncthreads();
    // cubic Hermite interpolation for save points in (t, t_next]
    if (s_ok[tt]) {
      float tOld = s_t[tt], hcs = s_hc[tt], tNew = s_tn[tt];
      float inv = 1.0f / fmaxf(hcs, 1e-12f);
      float yv[kDim], ynv[kDim], k1v[kDim], k7v[kDim];
      #pragma unroll
      for (int d = 0; d < kDim; ++d) {
        yv[d]  = sy[tt * LDD + d];
        ynv[d] = syn[tt * LDD + d];
        k1v[d] = hcs * sk[0][tt * LDD + d];
        k7v[d] = hcs * sk[6][tt * LDD + d];
      }
      #pragma unroll
      for (int q = 0; q < 4; ++q) {
        int n = 4 * gg + q;
        float te = sTe[n];
        if (te > tOld && te <= tNew + 1e-6f) {
          float sx = (te - tOld) * inv;
          float s2 = sx * sx, s3 = s2 * sx;
          float h00 = 2.f * s3 - 3.f * s2 + 1.f;
          float h10 = s3 - 2.f * s2 + sx;
          float h01 = -2.f * s3 + 3.f * s2;
          float h11 = s3 - s2;
          float* op = out + ((size_t)(bid * kTraj + tt) * kSave + n) * kDim;
          #pragma unroll
          for (int d = 0; d < kDim; ++d)
            op[d] = h00 * yv[d] + h10 * k1v[d] + h01 * ynv[d] + h11 * k7v[d];
        }
      }
    }
    __syncthreads();
    // state update (after interpolation has consumed old state)
    if (l80 && s_ok[ut]) { sy[uo] = syn[uo]; sk[0][uo] = sk[6][uo]; }
    if (tid < kTraj) { s_t[tid] = s_tn[tid]; s_h[tid] = s_hn[tid]; }
    __syncthreads();
  }
}

}  // namespace

extern "C" void kernel_launch(void* const* d_in, const int* in_sizes, int n_in,
                              void* d_out, int out_size, void* d_ws, size_t ws_size,
                              hipStream_t stream) {
  const float* y0 = (const float*)d_in[0];
  const float* te = (const float*)d_in[1];
  const float* W1 = (const float*)d_in[2];
  const float* b1 = (const float*)d_in[3];
  const float* W2 = (const float*)d_in[4];
  const float* b2 = (const float*)d_in[5];
  const float* W3 = (const float*)d_in[6];
  const float* b3 = (const float*)d_in[7];
  const float* W4 = (const float*)d_in[8];
  const float* b4 = (const float*)d_in[9];
  float* out = (float*)d_out;

  const int batch = in_sizes[0] / kDim;      // 4096
  const int blocks = batch / kTraj;          // 256
  hipLaunchKernelGGL(node_tsit5_kernel, dim3(blocks), dim3(kThreads), 0, stream,
                     y0, te, W1, b1, W2, b2, W3, b3, W4, b4, out);
}

// Round 3
// 148.530 us; speedup vs baseline: 2.9967x; 2.9967x over previous
//
#include <hip/hip_runtime.h>
#include <cmath>

namespace {

constexpr int kDim = 5;
constexpr int kSave = 64;
constexpr int kTraj = 16;      // trajectories per wave (= MFMA M)
constexpr int kMaxSteps = 64;
constexpr int ZS = 40;         // f16 stride: zb rows (80 B)
constexpr int HS = 80;         // f16 stride: activation planes (160 B -> even bank spread)
constexpr int SD = 8;          // f32 stride: small state rows

typedef _Float16 half8 __attribute__((ext_vector_type(8)));
typedef float f32x4 __attribute__((ext_vector_type(4)));

__device__ __forceinline__ float softplusf(float x) {
  // smooth, deterministic, ~1e-7 abs error: max(x,0) + log(1 + exp(-|x|))
  return fmaxf(x, 0.0f) + __logf(1.0f + __expf(-fabsf(x)));
}

__global__ __launch_bounds__(64, 1)
void node_tsit5_kernel(const float* __restrict__ gy0,
                       const float* __restrict__ gte,
                       const float* __restrict__ gW1, const float* __restrict__ gb1,
                       const float* __restrict__ gW2, const float* __restrict__ gb2,
                       const float* __restrict__ gW3, const float* __restrict__ gb3,
                       const float* __restrict__ gW4, const float* __restrict__ gb4,
                       float* __restrict__ out) {
  const float A21 = 0.161f;
  const float A31 = -0.008480655492356989f, A32 = 0.335480655492357f;
  const float A41 = 2.8971530571054935f, A42 = -6.359448489975075f, A43 = 4.3622954328695815f;
  const float A51 = 5.325864828439257f, A52 = -11.748883564062828f, A53 = 7.4955393428898365f,
              A54 = -0.09249506636175525f;
  const float A61 = 5.86145544294642f, A62 = -12.92096931784711f, A63 = 8.159367898576159f,
              A64 = -0.071584973281401f, A65 = -0.028269050394068383f;
  const float B1 = 0.09646076681806523f, B2 = 0.01f, B3 = 0.4798896504144996f,
              B4 = 1.379008574103742f, B5 = -3.290069515436081f, B6 = 2.324710524099774f;
  const float E1 = -0.00178001105222577714f, E2 = -0.0008164344596567469f,
              E3 = 0.007880878010261995f, E4 = -0.1447110071732629f, E5 = 0.5823571654525552f,
              E6 = -0.45808210592918697f, E7 = 0.015151515151515152f;

  __shared__ __align__(16) _Float16 zb[kTraj * ZS];    // layer-1 A input: [zhi(0..4)|zlo(5..9)|0]
  __shared__ __align__(16) _Float16 hiA[kTraj * HS], loA[kTraj * HS];
  __shared__ __align__(16) _Float16 hiB[kTraj * HS], loB[kTraj * HS];
  __shared__ float sTe[kSave];
  __shared__ float sY[kTraj * SD], sYN[kTraj * SD], sK1[kTraj * SD], sK7[kTraj * SD];
  __shared__ float sesq[kTraj * SD];
  __shared__ float s_hc[kTraj], s_tOld[kTraj], s_tn[kTraj];
  __shared__ int s_ok[kTraj], s_done[kTraj];

  const int ln = threadIdx.x;      // 0..63, one wave
  const int bid = blockIdx.x;
  const int quad = ln >> 4;
  const int col = ln & 15;
  const int row0 = quad * 4;       // C-layout rows 4*quad + r
  const bool cact = col < kDim;    // C-lane carries dim d = col

  // ---- one-time: weight B-fragments (plain f16) + biases into registers ----
  half8 w1c[4];
  half8 w2h[4][2], w3h[4][2], w4h[2];
  float c1v[4], c2v[4], c3v[4], c4v;
  #pragma unroll
  for (int nt = 0; nt < 4; ++nt) {
    int nn = nt * 16 + col;
    c1v[nt] = gb1[nn]; c2v[nt] = gb2[nn]; c3v[nt] = gb3[nn];
    #pragma unroll
    for (int j = 0; j < 8; ++j) {
      int kk = quad * 8 + j;
      float wv = 0.0f;
      if (kk < 5) wv = gW1[nn * 5 + kk];
      else if (kk < 10) wv = gW1[nn * 5 + (kk - 5)];
      w1c[nt][j] = (_Float16)wv;
    }
    #pragma unroll
    for (int kf = 0; kf < 2; ++kf)
      #pragma unroll
      for (int j = 0; j < 8; ++j) {
        int kk = kf * 32 + quad * 8 + j;
        w2h[nt][kf][j] = (_Float16)gW2[nn * 64 + kk];
        w3h[nt][kf][j] = (_Float16)gW3[nn * 64 + kk];
      }
  }
  c4v = cact ? gb4[col] : 0.0f;
  #pragma unroll
  for (int kf = 0; kf < 2; ++kf)
    #pragma unroll
    for (int j = 0; j < 8; ++j) {
      int kk = kf * 32 + quad * 8 + j;
      w4h[kf][j] = cact ? (_Float16)gW4[col * 64 + kk] : (_Float16)0.0f;
    }

  // ---- init LDS state ----
  for (int i = ln; i < kTraj * ZS; i += 64) zb[i] = (_Float16)0.0f;
  sTe[ln] = gte[ln];   // kSave == 64

  f32x4 syr, synr, kk[7];
  if (cact) {
    #pragma unroll
    for (int r = 0; r < 4; ++r) {
      float v = gy0[(size_t)(bid * kTraj + row0 + r) * kDim + col];
      syr[r] = v;
      sY[(row0 + r) * SD + col] = v;
      _Float16 hi = (_Float16)v;
      _Float16 lo = (_Float16)(v - (float)hi);
      zb[(row0 + r) * ZS + col] = hi;
      zb[(row0 + r) * ZS + col + 5] = lo;
    }
  }
  __syncthreads();

  const float t0v = sTe[0];
  const float t1v = sTe[kSave - 1];

  // initial output: y0 where te<=t0, else 0 (covers the re-poisoned buffer; interp
  // later overwrites covered points from the SAME lane -> program-order, no race)
  {
    int tt = ln & 15, g4 = ln >> 4;
    float yv[kDim];
    #pragma unroll
    for (int d = 0; d < kDim; ++d) yv[d] = sY[tt * SD + d];
    for (int i = 0; i < 16; ++i) {
      int n = g4 * 16 + i;
      float init = (sTe[n] <= t0v + 1e-6f) ? 1.0f : 0.0f;
      float* op = out + ((size_t)(bid * kTraj + tt) * kSave + n) * kDim;
      #pragma unroll
      for (int d = 0; d < kDim; ++d) op[d] = init * yv[d];
    }
  }

  // ---- MLP: zb -> k (C-layout f32x4, valid for col<5); split-f16 activations ----
  auto evalF = [&]() -> f32x4 {
    // layer 1: 5 -> 64, one MFMA/tile (K=32 packs Whi*(zhi+zlo))
    {
      half8 az = *(const half8*)(zb + col * ZS + quad * 8);
      #pragma unroll
      for (int nt = 0; nt < 4; ++nt) {
        f32x4 a = {c1v[nt], c1v[nt], c1v[nt], c1v[nt]};
        a = __builtin_amdgcn_mfma_f32_16x16x32_f16(az, w1c[nt], a, 0, 0, 0);
        int nn = nt * 16 + col;
        #pragma unroll
        for (int r = 0; r < 4; ++r) {
          float s = softplusf(a[r]);
          _Float16 hi = (_Float16)s;
          _Float16 lo = (_Float16)(s - (float)hi);
          hiA[(row0 + r) * HS + nn] = hi;
          loA[(row0 + r) * HS + nn] = lo;
        }
      }
    }
    __syncthreads();
    // layer 2: 64 -> 64 (A -> B), Whi*ahi + Whi*alo
    {
      half8 ah0 = *(const half8*)(hiA + col * HS + quad * 8);
      half8 ah1 = *(const half8*)(hiA + col * HS + 32 + quad * 8);
      half8 al0 = *(const half8*)(loA + col * HS + quad * 8);
      half8 al1 = *(const half8*)(loA + col * HS + 32 + quad * 8);
      #pragma unroll
      for (int nt = 0; nt < 4; ++nt) {
        f32x4 a = {c2v[nt], c2v[nt], c2v[nt], c2v[nt]};
        a = __builtin_amdgcn_mfma_f32_16x16x32_f16(ah0, w2h[nt][0], a, 0, 0, 0);
        a = __builtin_amdgcn_mfma_f32_16x16x32_f16(ah1, w2h[nt][1], a, 0, 0, 0);
        a = __builtin_amdgcn_mfma_f32_16x16x32_f16(al0, w2h[nt][0], a, 0, 0, 0);
        a = __builtin_amdgcn_mfma_f32_16x16x32_f16(al1, w2h[nt][1], a, 0, 0, 0);
        int nn = nt * 16 + col;
        #pragma unroll
        for (int r = 0; r < 4; ++r) {
          float s = softplusf(a[r]);
          _Float16 hi = (_Float16)s;
          _Float16 lo = (_Float16)(s - (float)hi);
          hiB[(row0 + r) * HS + nn] = hi;
          loB[(row0 + r) * HS + nn] = lo;
        }
      }
    }
    __syncthreads();
    // layer 3: 64 -> 64 (B -> A)
    {
      half8 ah0 = *(const half8*)(hiB + col * HS + quad * 8);
      half8 ah1 = *(const half8*)(hiB + col * HS + 32 + quad * 8);
      half8 al0 = *(const half8*)(loB + col * HS + quad * 8);
      half8 al1 = *(const half8*)(loB + col * HS + 32 + quad * 8);
      #pragma unroll
      for (int nt = 0; nt < 4; ++nt) {
        f32x4 a = {c3v[nt], c3v[nt], c3v[nt], c3v[nt]};
        a = __builtin_amdgcn_mfma_f32_16x16x32_f16(ah0, w3h[nt][0], a, 0, 0, 0);
        a = __builtin_amdgcn_mfma_f32_16x16x32_f16(ah1, w3h[nt][1], a, 0, 0, 0);
        a = __builtin_amdgcn_mfma_f32_16x16x32_f16(al0, w3h[nt][0], a, 0, 0, 0);
        a = __builtin_amdgcn_mfma_f32_16x16x32_f16(al1, w3h[nt][1], a, 0, 0, 0);
        int nn = nt * 16 + col;
        #pragma unroll
        for (int r = 0; r < 4; ++r) {
          float s = softplusf(a[r]);
          _Float16 hi = (_Float16)s;
          _Float16 lo = (_Float16)(s - (float)hi);
          hiA[(row0 + r) * HS + nn] = hi;
          loA[(row0 + r) * HS + nn] = lo;
        }
      }
    }
    __syncthreads();
    // layer 4: 64 -> 5 (single tile; cols >= 5 garbage, never used)
    f32x4 a = {c4v, c4v, c4v, c4v};
    {
      half8 ah0 = *(const half8*)(hiA + col * HS + quad * 8);
      half8 ah1 = *(const half8*)(hiA + col * HS + 32 + quad * 8);
      half8 al0 = *(const half8*)(loA + col * HS + quad * 8);
      half8 al1 = *(const half8*)(loA + col * HS + 32 + quad * 8);
      a = __builtin_amdgcn_mfma_f32_16x16x32_f16(ah0, w4h[0], a, 0, 0, 0);
      a = __builtin_amdgcn_mfma_f32_16x16x32_f16(ah1, w4h[1], a, 0, 0, 0);
      a = __builtin_amdgcn_mfma_f32_16x16x32_f16(al0, w4h[0], a, 0, 0, 0);
      a = __builtin_amdgcn_mfma_f32_16x16x32_f16(al1, w4h[1], a, 0, 0, 0);
    }
    __syncthreads();
    return a;
  };

  auto zwrite = [&](f32x4 z) {
    if (cact) {
      #pragma unroll
      for (int r = 0; r < 4; ++r) {
        _Float16 hi = (_Float16)z[r];
        _Float16 lo = (_Float16)(z[r] - (float)hi);
        zb[(row0 + r) * ZS + col] = hi;
        zb[(row0 + r) * ZS + col + 5] = lo;
      }
    }
    __syncthreads();
  };

  kk[0] = evalF();   // k1 = f(y0); FSAL thereafter

  float tcur = t0v, hcur = 0.1f;   // meaningful in lanes 0..15 (traj = ln)

  for (int step = 0; step < kMaxSteps; ++step) {
    if (ln < kTraj) {
      int dn = tcur >= t1v - 1e-6f;
      s_done[ln] = dn;
      s_hc[ln] = dn ? 0.0f : fminf(hcur, t1v - tcur);
      s_tOld[ln] = tcur;
    }
    __syncthreads();
    if (__ballot(s_done[ln & 15]) == ~0ull) break;   // uniform

    f32x4 hcr;
    if (cact) {
      #pragma unroll
      for (int r = 0; r < 4; ++r) hcr[r] = s_hc[row0 + r];
    }

    f32x4 z;
    #pragma unroll
    for (int r = 0; r < 4; ++r) z[r] = fmaf(hcr[r], A21 * kk[0][r], syr[r]);
    zwrite(z); kk[1] = evalF();

    #pragma unroll
    for (int r = 0; r < 4; ++r)
      z[r] = fmaf(hcr[r], fmaf(A32, kk[1][r], A31 * kk[0][r]), syr[r]);
    zwrite(z); kk[2] = evalF();

    #pragma unroll
    for (int r = 0; r < 4; ++r)
      z[r] = fmaf(hcr[r], fmaf(A43, kk[2][r], fmaf(A42, kk[1][r], A41 * kk[0][r])), syr[r]);
    zwrite(z); kk[3] = evalF();

    #pragma unroll
    for (int r = 0; r < 4; ++r)
      z[r] = fmaf(hcr[r], fmaf(A54, kk[3][r], fmaf(A53, kk[2][r],
                  fmaf(A52, kk[1][r], A51 * kk[0][r]))), syr[r]);
    zwrite(z); kk[4] = evalF();

    #pragma unroll
    for (int r = 0; r < 4; ++r)
      z[r] = fmaf(hcr[r], fmaf(A65, kk[4][r], fmaf(A64, kk[3][r], fmaf(A63, kk[2][r],
                  fmaf(A62, kk[1][r], A61 * kk[0][r])))), syr[r]);
    zwrite(z); kk[5] = evalF();

    #pragma unroll
    for (int r = 0; r < 4; ++r)
      synr[r] = fmaf(hcr[r], fmaf(B6, kk[5][r], fmaf(B5, kk[4][r], fmaf(B4, kk[3][r],
                 fmaf(B3, kk[2][r], fmaf(B2, kk[1][r], B1 * kk[0][r]))))), syr[r]);
    zwrite(synr); kk[6] = evalF();   // k7 (FSAL)

    // error + stash interp state (old y stays in sY until after interp)
    if (cact) {
      #pragma unroll
      for (int r = 0; r < 4; ++r) {
        float err = hcr[r] * fmaf(E7, kk[6][r], fmaf(E6, kk[5][r], fmaf(E5, kk[4][r],
                    fmaf(E4, kk[3][r], fmaf(E3, kk[2][r], fmaf(E2, kk[1][r], E1 * kk[0][r]))))));
        float sc = fmaf(1e-3f, fmaxf(fabsf(syr[r]), fabsf(synr[r])), 1e-6f);
        float rr = err / sc;
        int o = (row0 + r) * SD + col;
        sesq[o] = rr * rr;
        sYN[o] = synr[r];
        sK1[o] = kk[0][r];
        sK7[o] = kk[6][r];
      }
    }
    __syncthreads();
    if (ln < kTraj) {
      float s = 0.0f;
      #pragma unroll
      for (int d = 0; d < kDim; ++d) s += sesq[ln * SD + d];
      float enorm = sqrtf(s / 5.0f);
      float enc = fmaxf(enorm, 1e-10f);
      int accept = enorm <= 1.0f;
      float factor = fminf(fmaxf(0.9f * powf(enc, -0.2f), 0.2f), 10.0f);
      int dn = s_done[ln];
      int ok = accept && !dn;
      float hcc = s_hc[ln];
      float tn = ok ? tcur + hcc : tcur;
      s_tn[ln] = tn;
      s_ok[ln] = ok;
      tcur = tn;
      hcur = dn ? hcur : hcc * factor;
    }
    __syncthreads();
    // cubic Hermite interpolation for save points in (t, t_next]
    {
      int tt = ln & 15, g4 = ln >> 4;
      if (s_ok[tt]) {
        float tOld = s_tOld[tt], hcs = s_hc[tt], tNew = s_tn[tt];
        float inv = 1.0f / fmaxf(hcs, 1e-12f);
        float yv[kDim], ynv[kDim], k1v[kDim], k7v[kDim];
        #pragma unroll
        for (int d = 0; d < kDim; ++d) {
          yv[d] = sY[tt * SD + d];
          ynv[d] = sYN[tt * SD + d];
          k1v[d] = hcs * sK1[tt * SD + d];
          k7v[d] = hcs * sK7[tt * SD + d];
        }
        for (int i = 0; i < 16; ++i) {
          int n = g4 * 16 + i;
          float te = sTe[n];
          if (te > tOld && te <= tNew + 1e-6f) {
            float sx = (te - tOld) * inv;
            float s2 = sx * sx, s3 = s2 * sx;
            float h00 = 2.f * s3 - 3.f * s2 + 1.f;
            float h10 = s3 - 2.f * s2 + sx;
            float h01 = -2.f * s3 + 3.f * s2;
            float h11 = s3 - s2;
            float* op = out + ((size_t)(bid * kTraj + tt) * kSave + n) * kDim;
            #pragma unroll
            for (int d = 0; d < kDim; ++d)
              op[d] = h00 * yv[d] + h10 * k1v[d] + h01 * ynv[d] + h11 * k7v[d];
          }
        }
      }
    }
    __syncthreads();
    // FSAL + state update (after interp consumed old state)
    if (cact) {
      #pragma unroll
      for (int r = 0; r < 4; ++r) {
        int ok = s_ok[row0 + r];
        syr[r] = ok ? synr[r] : syr[r];
        kk[0][r] = ok ? kk[6][r] : kk[0][r];
        sY[(row0 + r) * SD + col] = syr[r];
      }
    }
    __syncthreads();
  }
}

}  // namespace

extern "C" void kernel_launch(void* const* d_in, const int* in_sizes, int n_in,
                              void* d_out, int out_size, void* d_ws, size_t ws_size,
                              hipStream_t stream) {
  const float* y0 = (const float*)d_in[0];
  const float* te = (const float*)d_in[1];
  const float* W1 = (const float*)d_in[2];
  const float* b1 = (const float*)d_in[3];
  const float* W2 = (const float*)d_in[4];
  const float* b2 = (const float*)d_in[5];
  const float* W3 = (const float*)d_in[6];
  const float* b3 = (const float*)d_in[7];
  const float* W4 = (const float*)d_in[8];
  const float* b4 = (const float*)d_in[9];
  float* out = (float*)d_out;

  const int batch = in_sizes[0] / kDim;      // 4096
  const int blocks = batch / kTraj;          // 256 single-wave blocks, ~1/CU
  hipLaunchKernelGGL(node_tsit5_kernel, dim3(blocks), dim3(64), 0, stream,
                     y0, te, W1, b1, W2, b2, W3, b3, W4, b4, out);
}

// Round 4
// 109.378 us; speedup vs baseline: 4.0694x; 1.3580x over previous
//
#include <hip/hip_runtime.h>
#include <cmath>

namespace {

constexpr int kDim = 5;
constexpr int kSave = 64;
constexpr int kTraj = 16;      // trajectories per block (= MFMA M)
constexpr int kThreads = 256;  // 4 waves; wave w owns neuron tile [16w,16w+16)
constexpr int kMaxSteps = 64;
constexpr int ZS = 40;         // f16 stride: zb rows (80 B)
constexpr int HS = 72;         // f16 stride: activation planes (144 B)
constexpr int SD = 8;          // f32 stride: small state rows

typedef _Float16 half8 __attribute__((ext_vector_type(8)));
typedef float f32x4 __attribute__((ext_vector_type(4)));

__device__ __forceinline__ float softplusf(float x) {
  return fmaxf(x, 0.0f) + __logf(1.0f + __expf(-fabsf(x)));
}

__global__ __launch_bounds__(kThreads, 1)
void node_tsit5_kernel(const float* __restrict__ gy0,
                       const float* __restrict__ gte,
                       const float* __restrict__ gW1, const float* __restrict__ gb1,
                       const float* __restrict__ gW2, const float* __restrict__ gb2,
                       const float* __restrict__ gW3, const float* __restrict__ gb3,
                       const float* __restrict__ gW4, const float* __restrict__ gb4,
                       float* __restrict__ out) {
  const float A21 = 0.161f;
  const float A31 = -0.008480655492356989f, A32 = 0.335480655492357f;
  const float A41 = 2.8971530571054935f, A42 = -6.359448489975075f, A43 = 4.3622954328695815f;
  const float A51 = 5.325864828439257f, A52 = -11.748883564062828f, A53 = 7.4955393428898365f,
              A54 = -0.09249506636175525f;
  const float A61 = 5.86145544294642f, A62 = -12.92096931784711f, A63 = 8.159367898576159f,
              A64 = -0.071584973281401f, A65 = -0.028269050394068383f;
  const float B1 = 0.09646076681806523f, B2 = 0.01f, B3 = 0.4798896504144996f,
              B4 = 1.379008574103742f, B5 = -3.290069515436081f, B6 = 2.324710524099774f;
  const float E1 = -0.00178001105222577714f, E2 = -0.0008164344596567469f,
              E3 = 0.007880878010261995f, E4 = -0.1447110071732629f, E5 = 0.5823571654525552f,
              E6 = -0.45808210592918697f, E7 = 0.015151515151515152f;

  __shared__ __align__(16) _Float16 zb[kTraj * ZS];    // L1 A input: [zhi(0..4)|zlo(5..9)|0]
  __shared__ __align__(16) _Float16 hiA[kTraj * HS], loA[kTraj * HS];
  __shared__ __align__(16) _Float16 hiB[kTraj * HS], loB[kTraj * HS];
  __shared__ float sTe[kSave];
  __shared__ float sY[kTraj * SD], sYN[kTraj * SD], sK1[kTraj * SD], sK7[kTraj * SD];
  __shared__ float sesq[kTraj * SD];
  __shared__ float s_hc[kTraj], s_tOld[kTraj], s_tn[kTraj];
  __shared__ int s_ok[kTraj], s_done[kTraj];

  const int tid = threadIdx.x;
  const int bid = blockIdx.x;
  const int w = tid >> 6;          // wave id = neuron tile
  const int ln = tid & 63;
  const int quad = ln >> 4;
  const int col = ln & 15;
  const int row0 = quad * 4;       // C-layout rows
  const int nn = (w << 4) | col;   // this wave's neuron for B-frag / C-col
  const bool cact = col < kDim;    // C-lane carries dim d = col (valid in every wave)
  const bool w0 = (w == 0);

  // ---- one-time: this wave's weight B-frags + biases; all waves hold W4 ----
  half8 w1c, w2h[2], w3h[2], w4h[2];
  #pragma unroll
  for (int j = 0; j < 8; ++j) {
    int kk2 = quad * 8 + j;
    float wv = 0.0f;
    if (kk2 < 5) wv = gW1[nn * 5 + kk2];
    else if (kk2 < 10) wv = gW1[nn * 5 + (kk2 - 5)];
    w1c[j] = (_Float16)wv;
  }
  #pragma unroll
  for (int kf = 0; kf < 2; ++kf)
    #pragma unroll
    for (int j = 0; j < 8; ++j) {
      int kk2 = kf * 32 + quad * 8 + j;
      w2h[kf][j] = (_Float16)gW2[nn * 64 + kk2];
      w3h[kf][j] = (_Float16)gW3[nn * 64 + kk2];
      w4h[kf][j] = cact ? (_Float16)gW4[col * 64 + kk2] : (_Float16)0.0f;
    }
  const float c1 = gb1[nn], c2 = gb2[nn], c3 = gb3[nn];
  const float c4 = cact ? gb4[col] : 0.0f;

  // ---- init LDS ----
  for (int i = tid; i < kTraj * ZS; i += kThreads) zb[i] = (_Float16)0.0f;
  if (tid < kSave) sTe[tid] = gte[tid];
  if (tid < kTraj * kDim) {   // t = tid&15, d = tid>>4
    int t = tid & 15, d = tid >> 4;
    float v = gy0[(size_t)(bid * kTraj + t) * kDim + d];
    sY[t * SD + d] = v;
    _Float16 hi = (_Float16)v;
    zb[t * ZS + d] = hi;
    zb[t * ZS + d + 5] = (_Float16)(v - (float)hi);
  }
  {
    float* ob = out + (size_t)bid * kTraj * kSave * kDim;
    for (int idx = tid; idx < kTraj * kSave * kDim; idx += kThreads) ob[idx] = 0.0f;
  }
  __syncthreads();

  const float t0v = sTe[0];
  const float t1v = sTe[kSave - 1];

  // y-state in registers, replicated in every wave (cact lanes: traj=row0+r, dim=col)
  f32x4 syr, synr, kk[7];
  if (cact) {
    #pragma unroll
    for (int r = 0; r < 4; ++r)
      syr[r] = gy0[(size_t)(bid * kTraj + row0 + r) * kDim + col];
  }

  // saves at/before t0 get y0 (same-lane overwrite later -> program order, no race)
  {
    int tt = tid & 15, gg = tid >> 4;
    float yv[kDim];
    #pragma unroll
    for (int d = 0; d < kDim; ++d) yv[d] = sY[tt * SD + d];
    #pragma unroll
    for (int q = 0; q < 4; ++q) {
      int n = 4 * gg + q;
      if (sTe[n] <= t0v + 1e-6f) {
        float* op = out + ((size_t)(bid * kTraj + tt) * kSave + n) * kDim;
        #pragma unroll
        for (int d = 0; d < kDim; ++d) op[d] = yv[d];
      }
    }
  }

  // ---- MLP: zb -> C-layout f32x4 (valid col<5); split-f16; same op order as R3 ----
  auto evalF = [&]() -> f32x4 {
    // L1: 5 -> 64 (K=32 packs Whi*(zhi+zlo)); this wave's 16 neurons
    {
      half8 az = *(const half8*)(zb + col * ZS + quad * 8);
      f32x4 a = {c1, c1, c1, c1};
      a = __builtin_amdgcn_mfma_f32_16x16x32_f16(az, w1c, a, 0, 0, 0);
      #pragma unroll
      for (int r = 0; r < 4; ++r) {
        float s = softplusf(a[r]);
        _Float16 hi = (_Float16)s;
        hiA[(row0 + r) * HS + nn] = hi;
        loA[(row0 + r) * HS + nn] = (_Float16)(s - (float)hi);
      }
    }
    __syncthreads();
    // L2: 64 -> 64 (A -> B)
    {
      half8 ah0 = *(const half8*)(hiA + col * HS + quad * 8);
      half8 ah1 = *(const half8*)(hiA + col * HS + 32 + quad * 8);
      half8 al0 = *(const half8*)(loA + col * HS + quad * 8);
      half8 al1 = *(const half8*)(loA + col * HS + 32 + quad * 8);
      f32x4 a = {c2, c2, c2, c2};
      a = __builtin_amdgcn_mfma_f32_16x16x32_f16(ah0, w2h[0], a, 0, 0, 0);
      a = __builtin_amdgcn_mfma_f32_16x16x32_f16(ah1, w2h[1], a, 0, 0, 0);
      a = __builtin_amdgcn_mfma_f32_16x16x32_f16(al0, w2h[0], a, 0, 0, 0);
      a = __builtin_amdgcn_mfma_f32_16x16x32_f16(al1, w2h[1], a, 0, 0, 0);
      #pragma unroll
      for (int r = 0; r < 4; ++r) {
        float s = softplusf(a[r]);
        _Float16 hi = (_Float16)s;
        hiB[(row0 + r) * HS + nn] = hi;
        loB[(row0 + r) * HS + nn] = (_Float16)(s - (float)hi);
      }
    }
    __syncthreads();
    // L3: 64 -> 64 (B -> A)
    {
      half8 ah0 = *(const half8*)(hiB + col * HS + quad * 8);
      half8 ah1 = *(const half8*)(hiB + col * HS + 32 + quad * 8);
      half8 al0 = *(const half8*)(loB + col * HS + quad * 8);
      half8 al1 = *(const half8*)(loB + col * HS + 32 + quad * 8);
      f32x4 a = {c3, c3, c3, c3};
      a = __builtin_amdgcn_mfma_f32_16x16x32_f16(ah0, w3h[0], a, 0, 0, 0);
      a = __builtin_amdgcn_mfma_f32_16x16x32_f16(ah1, w3h[1], a, 0, 0, 0);
      a = __builtin_amdgcn_mfma_f32_16x16x32_f16(al0, w3h[0], a, 0, 0, 0);
      a = __builtin_amdgcn_mfma_f32_16x16x32_f16(al1, w3h[1], a, 0, 0, 0);
      #pragma unroll
      for (int r = 0; r < 4; ++r) {
        float s = softplusf(a[r]);
        _Float16 hi = (_Float16)s;
        hiA[(row0 + r) * HS + nn] = hi;
        loA[(row0 + r) * HS + nn] = (_Float16)(s - (float)hi);
      }
    }
    __syncthreads();
    // L4: 64 -> 5 — redundantly computed by every wave (identical results)
    f32x4 a = {c4, c4, c4, c4};
    {
      half8 ah0 = *(const half8*)(hiA + col * HS + quad * 8);
      half8 ah1 = *(const half8*)(hiA + col * HS + 32 + quad * 8);
      half8 al0 = *(const half8*)(loA + col * HS + quad * 8);
      half8 al1 = *(const half8*)(loA + col * HS + 32 + quad * 8);
      a = __builtin_amdgcn_mfma_f32_16x16x32_f16(ah0, w4h[0], a, 0, 0, 0);
      a = __builtin_amdgcn_mfma_f32_16x16x32_f16(ah1, w4h[1], a, 0, 0, 0);
      a = __builtin_amdgcn_mfma_f32_16x16x32_f16(al0, w4h[0], a, 0, 0, 0);
      a = __builtin_amdgcn_mfma_f32_16x16x32_f16(al1, w4h[1], a, 0, 0, 0);
    }
    return a;   // no trailing barrier; caller's zwrite barrier orders hiA reuse
  };

  // z (C-layout regs, identical in all waves) -> zb; only wave 0 writes
  auto zwrite = [&](f32x4 z) {
    if (w0 && cact) {
      #pragma unroll
      for (int r = 0; r < 4; ++r) {
        _Float16 hi = (_Float16)z[r];
        zb[(row0 + r) * ZS + col] = hi;
        zb[(row0 + r) * ZS + col + 5] = (_Float16)(z[r] - (float)hi);
      }
    }
    __syncthreads();
  };

  kk[0] = evalF();   // k1 = f(y0); FSAL thereafter
  __syncthreads();   // order L4 reads of hiA before next L1 writes

  float tcur = t0v, hcur = 0.1f;   // lanes ln<16 of every wave (identical)

  for (int step = 0; step < kMaxSteps; ++step) {
    if (ln < kTraj) {
      int dn = tcur >= t1v - 1e-6f;
      float hc = dn ? 0.0f : fminf(hcur, t1v - tcur);
      if (w0) { s_done[ln] = dn; s_hc[ln] = hc; s_tOld[ln] = tcur; }
    }
    __syncthreads();
    if (__ballot(s_done[ln & 15]) == ~0ull) break;   // uniform across waves

    f32x4 hcr;
    #pragma unroll
    for (int r = 0; r < 4; ++r) hcr[r] = s_hc[row0 + r];

    f32x4 z;
    #pragma unroll
    for (int r = 0; r < 4; ++r) z[r] = fmaf(hcr[r], A21 * kk[0][r], syr[r]);
    zwrite(z); kk[1] = evalF();

    #pragma unroll
    for (int r = 0; r < 4; ++r)
      z[r] = fmaf(hcr[r], fmaf(A32, kk[1][r], A31 * kk[0][r]), syr[r]);
    zwrite(z); kk[2] = evalF();

    #pragma unroll
    for (int r = 0; r < 4; ++r)
      z[r] = fmaf(hcr[r], fmaf(A43, kk[2][r], fmaf(A42, kk[1][r], A41 * kk[0][r])), syr[r]);
    zwrite(z); kk[3] = evalF();

    #pragma unroll
    for (int r = 0; r < 4; ++r)
      z[r] = fmaf(hcr[r], fmaf(A54, kk[3][r], fmaf(A53, kk[2][r],
                  fmaf(A52, kk[1][r], A51 * kk[0][r]))), syr[r]);
    zwrite(z); kk[4] = evalF();

    #pragma unroll
    for (int r = 0; r < 4; ++r)
      z[r] = fmaf(hcr[r], fmaf(A65, kk[4][r], fmaf(A64, kk[3][r], fmaf(A63, kk[2][r],
                  fmaf(A62, kk[1][r], A61 * kk[0][r])))), syr[r]);
    zwrite(z); kk[5] = evalF();

    #pragma unroll
    for (int r = 0; r < 4; ++r)
      synr[r] = fmaf(hcr[r], fmaf(B6, kk[5][r], fmaf(B5, kk[4][r], fmaf(B4, kk[3][r],
                 fmaf(B3, kk[2][r], fmaf(B2, kk[1][r], B1 * kk[0][r]))))), syr[r]);
    zwrite(synr); kk[6] = evalF();   // k7 (FSAL)

    // error + stash interp state (wave 0 writes; old y stays in sY until after interp)
    if (w0 && cact) {
      #pragma unroll
      for (int r = 0; r < 4; ++r) {
        float err = hcr[r] * fmaf(E7, kk[6][r], fmaf(E6, kk[5][r], fmaf(E5, kk[4][r],
                    fmaf(E4, kk[3][r], fmaf(E3, kk[2][r], fmaf(E2, kk[1][r], E1 * kk[0][r]))))));
        float sc = fmaf(1e-3f, fmaxf(fabsf(syr[r]), fabsf(synr[r])), 1e-6f);
        float rr = err / sc;
        int o = (row0 + r) * SD + col;
        sesq[o] = rr * rr;
        sYN[o] = synr[r];
        sK1[o] = kk[0][r];
        sK7[o] = kk[6][r];
      }
    }
    __syncthreads();
    if (ln < kTraj) {   // every wave computes identical control update
      float s = 0.0f;
      #pragma unroll
      for (int d = 0; d < kDim; ++d) s += sesq[ln * SD + d];
      float enorm = sqrtf(s / 5.0f);
      float enc = fmaxf(enorm, 1e-10f);
      int accept = enorm <= 1.0f;
      float factor = fminf(fmaxf(0.9f * powf(enc, -0.2f), 0.2f), 10.0f);
      int dn = s_done[ln];
      int ok = accept && !dn;
      float hc = s_hc[ln];
      float tn = ok ? tcur + hc : tcur;
      if (w0) { s_tn[ln] = tn; s_ok[ln] = ok; }
      tcur = tn;
      hcur = dn ? hcur : hc * factor;
    }
    __syncthreads();
    // cubic Hermite interpolation for save points in (t, t_next]; 256 threads
    {
      int tt = tid & 15, gg = tid >> 4;
      if (s_ok[tt]) {
        float tOld = s_tOld[tt], hcs = s_hc[tt], tNew = s_tn[tt];
        float inv = 1.0f / fmaxf(hcs, 1e-12f);
        float yv[kDim], ynv[kDim], k1v[kDim], k7v[kDim];
        #pragma unroll
        for (int d = 0; d < kDim; ++d) {
          yv[d] = sY[tt * SD + d];
          ynv[d] = sYN[tt * SD + d];
          k1v[d] = hcs * sK1[tt * SD + d];
          k7v[d] = hcs * sK7[tt * SD + d];
        }
        #pragma unroll
        for (int q = 0; q < 4; ++q) {
          int n = 4 * gg + q;
          float te = sTe[n];
          if (te > tOld && te <= tNew + 1e-6f) {
            float sx = (te - tOld) * inv;
            float s2 = sx * sx, s3 = s2 * sx;
            float h00 = 2.f * s3 - 3.f * s2 + 1.f;
            float h10 = s3 - 2.f * s2 + sx;
            float h01 = -2.f * s3 + 3.f * s2;
            float h11 = s3 - s2;
            float* op = out + ((size_t)(bid * kTraj + tt) * kSave + n) * kDim;
            #pragma unroll
            for (int d = 0; d < kDim; ++d)
              op[d] = h00 * yv[d] + h10 * k1v[d] + h01 * ynv[d] + h11 * k7v[d];
          }
        }
      }
    }
    __syncthreads();
    // FSAL + state update (after interp consumed old sY)
    if (cact) {
      #pragma unroll
      for (int r = 0; r < 4; ++r) {
        int ok = s_ok[row0 + r];
        syr[r] = ok ? synr[r] : syr[r];
        kk[0][r] = ok ? kk[6][r] : kk[0][r];
        if (w0) sY[(row0 + r) * SD + col] = syr[r];
      }
    }
    __syncthreads();
  }
}

}  // namespace

extern "C" void kernel_launch(void* const* d_in, const int* in_sizes, int n_in,
                              void* d_out, int out_size, void* d_ws, size_t ws_size,
                              hipStream_t stream) {
  const float* y0 = (const float*)d_in[0];
  const float* te = (const float*)d_in[1];
  const float* W1 = (const float*)d_in[2];
  const float* b1 = (const float*)d_in[3];
  const float* W2 = (const float*)d_in[4];
  const float* b2 = (const float*)d_in[5];
  const float* W3 = (const float*)d_in[6];
  const float* b3 = (const float*)d_in[7];
  const float* W4 = (const float*)d_in[8];
  const float* b4 = (const float*)d_in[9];
  float* out = (float*)d_out;

  const int batch = in_sizes[0] / kDim;      // 4096
  const int blocks = batch / kTraj;          // 256 blocks x 4 waves = 1 block/CU
  hipLaunchKernelGGL(node_tsit5_kernel, dim3(blocks), dim3(kThreads), 0, stream,
                     y0, te, W1, b1, W2, b2, W3, b3, W4, b4, out);
}